// Round 1
// baseline (23182.689 us; speedup 1.0000x reference)
//
#include <hip/hip_runtime.h>
#include <hip/hip_bf16.h>
#include <math.h>

// Problem constants (match reference)
#define Bc 2
#define Tc 2048
#define Cc 1024
#define Hc 16
#define Dc 64
// SCALE = 1/8, GAMMA = 8

// ---------------------------------------------------------------------------
// Generic f32 tiled GEMM: C[M,N] = A[M,K] @ W[K,N]; M,N,K multiples of 64/16.
// 64x64 tile, 256 threads, 4x4 micro-tile, BK=16.
// ---------------------------------------------------------------------------
__global__ __launch_bounds__(256) void gemm64(const float* __restrict__ A,
                                              const float* __restrict__ W,
                                              float* __restrict__ Cout,
                                              int M, int N, int K)
{
    __shared__ float As[16][64];   // [k][m]
    __shared__ float Bs[16][64];   // [k][n]
    const int tid = threadIdx.x;
    const int tx = tid & 15;       // n dir
    const int ty = tid >> 4;       // m dir
    const int m0 = blockIdx.y * 64;
    const int n0 = blockIdx.x * 64;

    const int arow = tid >> 2;        // 0..63
    const int acol = (tid & 3) * 4;   // 0,4,8,12
    const int brow = tid >> 4;        // 0..15
    const int bcol = (tid & 15) * 4;  // 0..60

    float acc[4][4] = {};

    for (int k0 = 0; k0 < K; k0 += 16) {
        float4 av = *(const float4*)&A[(size_t)(m0 + arow) * K + k0 + acol];
        As[acol + 0][arow] = av.x;
        As[acol + 1][arow] = av.y;
        As[acol + 2][arow] = av.z;
        As[acol + 3][arow] = av.w;
        float4 bv = *(const float4*)&W[(size_t)(k0 + brow) * N + n0 + bcol];
        *(float4*)&Bs[brow][bcol] = bv;
        __syncthreads();
#pragma unroll
        for (int k = 0; k < 16; ++k) {
            float4 a = *(const float4*)&As[k][ty * 4];
            float4 b = *(const float4*)&Bs[k][tx * 4];
            float am[4] = {a.x, a.y, a.z, a.w};
            float bn[4] = {b.x, b.y, b.z, b.w};
#pragma unroll
            for (int i = 0; i < 4; ++i)
#pragma unroll
                for (int j = 0; j < 4; ++j)
                    acc[i][j] += am[i] * bn[j];
        }
        __syncthreads();
    }
#pragma unroll
    for (int i = 0; i < 4; ++i) {
        float4 o = make_float4(acc[i][0], acc[i][1], acc[i][2], acc[i][3]);
        *(float4*)&Cout[(size_t)(m0 + ty * 4 + i) * N + n0 + tx * 4] = o;
    }
}

// ---------------------------------------------------------------------------
// k_raw (B,T,2C) -> k2 (B,H,T,128): [softplus(amp)*cos(ph) | softplus(amp)*sin(ph)]
// ---------------------------------------------------------------------------
__global__ __launch_bounds__(256) void k_transform(const float* __restrict__ k_raw,
                                                   float* __restrict__ k2)
{
    int idx = blockIdx.x * blockDim.x + threadIdx.x;  // over B*H*T*D = 4,194,304
    if (idx >= Bc * Hc * Tc * Dc) return;
    int d = idx & 63;
    int t = (idx >> 6) & (Tc - 1);
    int h = (idx >> 17) & (Hc - 1);
    int b = idx >> 21;

    size_t base = (size_t)(b * Tc + t) * (2 * Cc) + h * Dc + d;
    float amp = k_raw[base];
    float ph  = k_raw[base + Cc];
    float sp = fmaxf(amp, 0.f) + log1pf(expf(-fabsf(amp)));
    float sn, cs;
    sincosf(ph, &sn, &cs);
    size_t o = ((size_t)(b * Hc + h) * Tc + t) * 128 + d;
    k2[o]      = sp * cs;
    k2[o + 64] = sp * sn;
}

// ---------------------------------------------------------------------------
// Flash-style causal attention with theta gate.
// Grid (T/32, H, B), 256 threads. Q-tile = 32 rows, streamed K/V tiles of 32.
// Q transformed (softplus/cos/sin, *SCALE) on load from q_raw.
// Output written in (B,T,C) layout for the final GEMM.
// ---------------------------------------------------------------------------
__global__ __launch_bounds__(256) void moire_attn(const float* __restrict__ q_raw,
                                                  const float* __restrict__ k2,
                                                  const float* __restrict__ v_raw,
                                                  const float* __restrict__ theta,
                                                  float* __restrict__ att_out)
{
    __shared__ float Qs[32][128];
    __shared__ float Ks[32][128];
    __shared__ float Vs[32][64];
    __shared__ float Ss[32][32];

    const int tid = threadIdx.x;
    const int qt = blockIdx.x;   // 0..63
    const int h  = blockIdx.y;
    const int b  = blockIdx.z;
    const int q0 = qt * 32;
    const float th = theta[h];

    // Load + transform Q tile: 32 rows x 64 (amp,ph) pairs -> 128 cols
#pragma unroll
    for (int i = 0; i < 8; ++i) {
        int e = tid + i * 256;          // 0..2047
        int r = e >> 6, d2 = e & 63;
        size_t base = (size_t)(b * Tc + q0 + r) * (2 * Cc) + h * Dc + d2;
        float amp = q_raw[base];
        float ph  = q_raw[base + Cc];
        float sp = fmaxf(amp, 0.f) + log1pf(expf(-fabsf(amp)));
        float sn, cs;
        sincosf(ph, &sn, &cs);
        Qs[r][d2]      = sp * cs * 0.125f;   // SCALE folded into Q
        Qs[r][d2 + 64] = sp * sn * 0.125f;
    }

    const int r  = tid >> 3;        // row 0..31 (same row for score + O mapping)
    const int sg = (tid & 7) * 4;   // 4 score columns
    const int cg = (tid & 7) * 8;   // 8 output columns
    const int t_glob = q0 + r;

    float m = -INFINITY, l = 0.f;
    float o[8] = {};

    for (int jt = 0; jt <= qt; ++jt) {
        const int s0 = jt * 32;
        // Load K tile (32x128) and V tile (32x64)
#pragma unroll
        for (int i = 0; i < 16; ++i) {
            int e = tid + i * 256;      // 0..4095
            int rr = e >> 7, dd = e & 127;
            Ks[rr][dd] = k2[((size_t)(b * Hc + h) * Tc + s0 + rr) * 128 + dd];
        }
#pragma unroll
        for (int i = 0; i < 8; ++i) {
            int e = tid + i * 256;      // 0..2047
            int rr = e >> 6, dd = e & 63;
            Vs[rr][dd] = v_raw[(size_t)(b * Tc + s0 + rr) * Cc + h * Dc + dd];
        }
        __syncthreads();

        // Scores (4 per thread)
        float sc[4];
#pragma unroll
        for (int js = 0; js < 4; ++js) {
            int sl = sg + js;
            float dot = 0.f;
#pragma unroll
            for (int d4 = 0; d4 < 128; d4 += 4) {
                float4 qv = *(const float4*)&Qs[r][d4];
                float4 kv = *(const float4*)&Ks[sl][d4];
                dot += qv.x * kv.x + qv.y * kv.y + qv.z * kv.z + qv.w * kv.w;
            }
            int s_glob = s0 + sl;
            float g = cosf(th * (float)(s_glob - t_glob) * 0.125f);
            sc[js] = (s_glob <= t_glob) ? dot * g : -INFINITY;
        }

        // Online softmax: row reductions across the 8 lanes owning this row
        float tm = fmaxf(fmaxf(sc[0], sc[1]), fmaxf(sc[2], sc[3]));
#pragma unroll
        for (int off = 1; off < 8; off <<= 1)
            tm = fmaxf(tm, __shfl_xor(tm, off, 8));
        float mn = fmaxf(m, tm);
        float alpha = expf(m - mn);     // m=-inf first iter -> alpha=0
        float psum = 0.f;
#pragma unroll
        for (int js = 0; js < 4; ++js) {
            float pp = expf(sc[js] - mn);   // masked -> exp(-inf)=0
            Ss[r][sg + js] = pp;
            psum += pp;
        }
#pragma unroll
        for (int off = 1; off < 8; off <<= 1)
            psum += __shfl_xor(psum, off, 8);
        l = l * alpha + psum;
        m = mn;
#pragma unroll
        for (int j = 0; j < 8; ++j) o[j] *= alpha;
        __syncthreads();

        // O += P @ V
#pragma unroll
        for (int s = 0; s < 32; ++s) {
            float pv = Ss[r][s];
            float4 v0 = *(const float4*)&Vs[s][cg];
            float4 v1 = *(const float4*)&Vs[s][cg + 4];
            o[0] += pv * v0.x; o[1] += pv * v0.y; o[2] += pv * v0.z; o[3] += pv * v0.w;
            o[4] += pv * v1.x; o[5] += pv * v1.y; o[6] += pv * v1.z; o[7] += pv * v1.w;
        }
        __syncthreads();
    }

    float inv = 1.f / l;
    float4 o0 = make_float4(o[0] * inv, o[1] * inv, o[2] * inv, o[3] * inv);
    float4 o1 = make_float4(o[4] * inv, o[5] * inv, o[6] * inv, o[7] * inv);
    size_t ob = (size_t)(b * Tc + t_glob) * Cc + h * Dc + cg;
    *(float4*)&att_out[ob]     = o0;
    *(float4*)&att_out[ob + 4] = o1;
}

// ---------------------------------------------------------------------------
extern "C" void kernel_launch(void* const* d_in, const int* in_sizes, int n_in,
                              void* d_out, int out_size, void* d_ws, size_t ws_size,
                              hipStream_t stream)
{
    const float* x     = (const float*)d_in[0];   // (B,T,C)
    const float* Wq    = (const float*)d_in[1];   // (C,2C)
    const float* Wk    = (const float*)d_in[2];   // (C,2C)
    const float* Wv    = (const float*)d_in[3];   // (C,C)
    const float* Wo    = (const float*)d_in[4];   // (C,C)
    const float* theta = (const float*)d_in[5];   // (H,)
    float* out = (float*)d_out;                   // (B,T,C) f32

    const int M = Bc * Tc;                        // 4096
    float* q_raw = (float*)d_ws;                  // M x 2C  = 8M floats
    float* k_raw = q_raw + (size_t)M * 2 * Cc;    // M x 2C  = 8M floats
    float* k2    = k_raw + (size_t)M * 2 * Cc;    // B*H*T*128 = 8M floats
    float* v_raw = k2    + (size_t)M * 2 * Cc;    // M x C   = 4M floats
    float* att   = k_raw;                         // reuse k_raw after k2 built
    // total ws use: 28M floats = 112 MB

    // Projections
    gemm64<<<dim3(2 * Cc / 64, M / 64), 256, 0, stream>>>(x, Wq, q_raw, M, 2 * Cc, Cc);
    gemm64<<<dim3(2 * Cc / 64, M / 64), 256, 0, stream>>>(x, Wk, k_raw, M, 2 * Cc, Cc);
    gemm64<<<dim3(Cc / 64, M / 64), 256, 0, stream>>>(x, Wv, v_raw, M, Cc, Cc);

    // K transform (k_raw free for reuse afterwards)
    k_transform<<<(Bc * Hc * Tc * Dc) / 256, 256, 0, stream>>>(k_raw, k2);

    // Flash attention with theta gate
    moire_attn<<<dim3(Tc / 32, Hc, Bc), 256, 0, stream>>>(q_raw, k2, v_raw, theta, att);

    // Output projection
    gemm64<<<dim3(Cc / 64, M / 64), 256, 0, stream>>>(att, Wo, out, M, Cc, Cc);
}

// Round 2
// 971.249 us; speedup vs baseline: 23.8689x; 23.8689x over previous
//
#include <hip/hip_runtime.h>
#include <hip/hip_bf16.h>
#include <math.h>

// Problem constants
#define Bc 2
#define Tc 2048
#define Cc 1024
#define Hc 16
#define Dc 64
// SCALE = 1/8, GAMMA = 8

typedef __attribute__((ext_vector_type(8))) short short8;   // 8 bf16 (4 VGPRs)
typedef __attribute__((ext_vector_type(4))) float f32x4;    // MFMA C/D frag

__device__ __forceinline__ short f2bf(float x) {
    unsigned u = __float_as_uint(x);
    u += 0x7fff + ((u >> 16) & 1);      // RNE
    return (short)(u >> 16);
}

// ---------------------------------------------------------------------------
// f32 tiled GEMM (unchanged from R1): C[M,N] = A[M,K] @ W[K,N]
// ---------------------------------------------------------------------------
__global__ __launch_bounds__(256) void gemm64(const float* __restrict__ A,
                                              const float* __restrict__ W,
                                              float* __restrict__ Cout,
                                              int M, int N, int K)
{
    __shared__ float As[16][64];
    __shared__ float Bs[16][64];
    const int tid = threadIdx.x;
    const int tx = tid & 15;
    const int ty = tid >> 4;
    const int m0 = blockIdx.y * 64;
    const int n0 = blockIdx.x * 64;

    const int arow = tid >> 2;
    const int acol = (tid & 3) * 4;
    const int brow = tid >> 4;
    const int bcol = (tid & 15) * 4;

    float acc[4][4] = {};

    for (int k0 = 0; k0 < K; k0 += 16) {
        float4 av = *(const float4*)&A[(size_t)(m0 + arow) * K + k0 + acol];
        As[acol + 0][arow] = av.x;
        As[acol + 1][arow] = av.y;
        As[acol + 2][arow] = av.z;
        As[acol + 3][arow] = av.w;
        float4 bv = *(const float4*)&W[(size_t)(k0 + brow) * N + n0 + bcol];
        *(float4*)&Bs[brow][bcol] = bv;
        __syncthreads();
#pragma unroll
        for (int k = 0; k < 16; ++k) {
            float4 a = *(const float4*)&As[k][ty * 4];
            float4 b = *(const float4*)&Bs[k][tx * 4];
            float am[4] = {a.x, a.y, a.z, a.w};
            float bn[4] = {b.x, b.y, b.z, b.w};
#pragma unroll
            for (int i = 0; i < 4; ++i)
#pragma unroll
                for (int j = 0; j < 4; ++j)
                    acc[i][j] += am[i] * bn[j];
        }
        __syncthreads();
    }
#pragma unroll
    for (int i = 0; i < 4; ++i) {
        float4 o = make_float4(acc[i][0], acc[i][1], acc[i][2], acc[i][3]);
        *(float4*)&Cout[(size_t)(m0 + ty * 4 + i) * N + n0 + tx * 4] = o;
    }
}

// ---------------------------------------------------------------------------
// raw (B,T,2C) f32 -> out2 (B,H,T,128) bf16 = [sp*cos(ph) | sp*sin(ph)] * scale
// ---------------------------------------------------------------------------
__global__ __launch_bounds__(256) void qk_transform(const float* __restrict__ raw,
                                                    short* __restrict__ out2,
                                                    float scale)
{
    int idx = blockIdx.x * 256 + threadIdx.x;   // B*H*T*64 = 2^22
    int d = idx & 63;
    int t = (idx >> 6) & (Tc - 1);
    int h = (idx >> 17) & (Hc - 1);
    int b = idx >> 21;
    size_t base = (size_t)(b * Tc + t) * (2 * Cc) + h * Dc + d;
    float amp = raw[base], ph = raw[base + Cc];
    float sp = fmaxf(amp, 0.f) + log1pf(expf(-fabsf(amp)));
    float sn, cs;
    sincosf(ph, &sn, &cs);
    size_t o = ((size_t)(b * Hc + h) * Tc + t) * 128 + d;
    out2[o]      = f2bf(sp * cs * scale);
    out2[o + 64] = f2bf(sp * sn * scale);
}

// ---------------------------------------------------------------------------
// v_raw (B,T,C) f32 -> v2t (B,H,D,T) bf16  (transpose so V B-frags are rows)
// ---------------------------------------------------------------------------
__global__ __launch_bounds__(256) void vtrans(const float* __restrict__ v_raw,
                                              short* __restrict__ v2t)
{
    __shared__ short tile[64][65];
    const int t0 = blockIdx.x * 64, h = blockIdx.y, b = blockIdx.z;
    const int tid = threadIdx.x;
#pragma unroll
    for (int i = 0; i < 4; ++i) {
        int e = i * 256 + tid;             // 0..1023
        int t = e >> 4, d4 = (e & 15) * 4;
        float4 v = *(const float4*)&v_raw[(size_t)(b * Tc + t0 + t) * Cc + h * Dc + d4];
        tile[t][d4]     = f2bf(v.x);
        tile[t][d4 + 1] = f2bf(v.y);
        tile[t][d4 + 2] = f2bf(v.z);
        tile[t][d4 + 3] = f2bf(v.w);
    }
    __syncthreads();
#pragma unroll
    for (int i = 0; i < 16; ++i) {
        int e = i * 256 + tid;             // 0..4095
        int d = e >> 6, t = e & 63;
        v2t[((size_t)(b * Hc + h) * Dc + d) * Tc + t0 + t] = tile[t][d];
    }
}

// ---------------------------------------------------------------------------
// MFMA flash attention with post-MFMA theta gate.
// Grid (T/64, H, B), 256 threads = 4 waves; wave handles 16 q-rows.
// LDS row pitches 136/72 shorts -> 68/36-word strides -> 2-way (free).
// ---------------------------------------------------------------------------
__global__ __launch_bounds__(256, 4) void moire_attn_mfma(
    const short* __restrict__ q2, const short* __restrict__ k2,
    const short* __restrict__ v2t, const float* __restrict__ theta,
    float* __restrict__ att)
{
    __shared__ short Ks[64 * 136];        // K tile: 64 s-rows x 128 dims (+8 pad)
    __shared__ short Vt[64 * 72];         // V tile: 64 d-rows x 64 s   (+8 pad)
    __shared__ short Ps[4 * 16 * 72];     // per-wave P: 16 q-rows x 64 s (+8 pad)

    const int tid = threadIdx.x;
    const int wave = tid >> 6, lane = tid & 63;
    const int quad = lane >> 4, c = lane & 15;
    const int qx = blockIdx.x, h = blockIdx.y, b = blockIdx.z;
    const int q0 = qx * 64;
    const float th = theta[h];

    // Q A-frags from global: A[m=c][k=quad*8+j], 4 chunks of K=32
    const int qrow = q0 + wave * 16 + c;
    const short* qp = q2 + ((size_t)(b * Hc + h) * Tc + qrow) * 128;
    short8 qf[4];
#pragma unroll
    for (int i = 0; i < 4; ++i)
        qf[i] = *(const short8*)(qp + i * 32 + quad * 8);

    f32x4 o_acc[4];
    float m_r[4], l_r[4];
#pragma unroll
    for (int i = 0; i < 4; ++i) {
        o_acc[i] = (f32x4){0.f, 0.f, 0.f, 0.f};
        m_r[i] = -INFINITY;
        l_r[i] = 0.f;
    }

    const short* k2b = k2 + (size_t)(b * Hc + h) * Tc * 128;
    const short* v2b = v2t + (size_t)(b * Hc + h) * Dc * Tc;
    short* Pw = &Ps[wave * 16 * 72];

    for (int jt = 0; jt <= qx; ++jt) {
        const int s0 = jt * 64;
        // stage K tile (64 x 128 bf16), coalesced 16B per lane
#pragma unroll
        for (int i = 0; i < 4; ++i) {
            int ch = i * 256 + tid;            // 1024 chunks
            int row = ch >> 4, c8 = (ch & 15) * 8;
            *(short8*)&Ks[row * 136 + c8] =
                *(const short8*)(k2b + (size_t)(s0 + row) * 128 + c8);
        }
        // stage V tile (64 d-rows x 64 s)
#pragma unroll
        for (int i = 0; i < 2; ++i) {
            int ch = i * 256 + tid;            // 512 chunks
            int row = ch >> 3, c8 = (ch & 7) * 8;
            *(short8*)&Vt[row * 72 + c8] =
                *(const short8*)(v2b + (size_t)row * Tc + s0 + c8);
        }
        __syncthreads();

        // S = Q K^T : 4 n-tiles x 4 K-chunks of MFMA
        f32x4 s_acc[4];
#pragma unroll
        for (int nt = 0; nt < 4; ++nt) {
            f32x4 acc = {0.f, 0.f, 0.f, 0.f};
#pragma unroll
            for (int kk = 0; kk < 4; ++kk) {
                short8 kf = *(const short8*)&Ks[(nt * 16 + c) * 136 + kk * 32 + quad * 8];
                acc = __builtin_amdgcn_mfma_f32_16x16x32_bf16(qf[kk], kf, acc, 0, 0, 0);
            }
            s_acc[nt] = acc;
        }

        // theta gate + causal mask (C layout: row=quad*4+reg, col=c)
        const int t_base = q0 + wave * 16 + quad * 4;
        const bool diag = (jt == qx);
        float sv[4][4];
#pragma unroll
        for (int nt = 0; nt < 4; ++nt) {
            int s_g = s0 + nt * 16 + c;
#pragma unroll
            for (int reg = 0; reg < 4; ++reg) {
                int t_g = t_base + reg;
                float v = s_acc[nt][reg] * __cosf(th * 0.125f * (float)(s_g - t_g));
                if (diag && s_g > t_g) v = -INFINITY;
                sv[nt][reg] = v;
            }
        }

        // online softmax (rows live in 16-lane quad groups)
        float mn[4], al[4], rs[4];
#pragma unroll
        for (int reg = 0; reg < 4; ++reg) {
            float rm = fmaxf(fmaxf(sv[0][reg], sv[1][reg]),
                             fmaxf(sv[2][reg], sv[3][reg]));
#pragma unroll
            for (int off = 1; off < 16; off <<= 1)
                rm = fmaxf(rm, __shfl_xor(rm, off));
            mn[reg] = fmaxf(m_r[reg], rm);
            al[reg] = __expf(m_r[reg] - mn[reg]);   // -inf -> 0 first tile
            rs[reg] = 0.f;
        }
#pragma unroll
        for (int nt = 0; nt < 4; ++nt)
#pragma unroll
            for (int reg = 0; reg < 4; ++reg) {
                float p = __expf(sv[nt][reg] - mn[reg]);  // masked -> 0
                rs[reg] += p;
                Pw[(quad * 4 + reg) * 72 + nt * 16 + c] = f2bf(p);
            }
#pragma unroll
        for (int reg = 0; reg < 4; ++reg) {
#pragma unroll
            for (int off = 1; off < 16; off <<= 1)
                rs[reg] += __shfl_xor(rs[reg], off);
            l_r[reg] = l_r[reg] * al[reg] + rs[reg];
            m_r[reg] = mn[reg];
        }
#pragma unroll
        for (int nt = 0; nt < 4; ++nt)
#pragma unroll
            for (int reg = 0; reg < 4; ++reg)
                o_acc[nt][reg] *= al[reg];

        // O += P V : P A-frags from per-wave LDS, V B-frags from Vt rows
#pragma unroll
        for (int nt = 0; nt < 4; ++nt) {
            f32x4 acc = o_acc[nt];
#pragma unroll
            for (int kk = 0; kk < 2; ++kk) {
                short8 pf = *(const short8*)&Pw[c * 72 + kk * 32 + quad * 8];
                short8 vf = *(const short8*)&Vt[(nt * 16 + c) * 72 + kk * 32 + quad * 8];
                acc = __builtin_amdgcn_mfma_f32_16x16x32_bf16(pf, vf, acc, 0, 0, 0);
            }
            o_acc[nt] = acc;
        }
        __syncthreads();
    }

    // epilogue: normalize, write (B,T,C) f32
#pragma unroll
    for (int reg = 0; reg < 4; ++reg) {
        float inv = 1.f / l_r[reg];
        int t_g = q0 + wave * 16 + quad * 4 + reg;
#pragma unroll
        for (int nt = 0; nt < 4; ++nt)
            att[(size_t)(b * Tc + t_g) * Cc + h * Dc + nt * 16 + c] =
                o_acc[nt][reg] * inv;
    }
}

// ---------------------------------------------------------------------------
extern "C" void kernel_launch(void* const* d_in, const int* in_sizes, int n_in,
                              void* d_out, int out_size, void* d_ws, size_t ws_size,
                              hipStream_t stream)
{
    const float* x     = (const float*)d_in[0];
    const float* Wq    = (const float*)d_in[1];
    const float* Wk    = (const float*)d_in[2];
    const float* Wv    = (const float*)d_in[3];
    const float* Wo    = (const float*)d_in[4];
    const float* theta = (const float*)d_in[5];
    float* out = (float*)d_out;

    const int M = Bc * Tc;                               // 4096
    const size_t n8M = (size_t)M * 2 * Cc;               // 8,388,608
    float* q_raw = (float*)d_ws;                         // 32 MB [att reuses]
    float* k_raw = q_raw + n8M;                          // 32 MB [v2t reuses]
    float* v_raw = k_raw + n8M;                          // 16 MB
    short* q2    = (short*)(v_raw + n8M / 2);            // 16 MB (B,H,T,128)
    short* k2    = q2 + n8M;                             // 16 MB (B,H,T,128)
    short* v2t   = (short*)k_raw;                        // 8 MB  (B,H,D,T)
    float* att   = q_raw;                                // 16 MB (B,T,C)
    // total: 112 MB

    gemm64<<<dim3(2 * Cc / 64, M / 64), 256, 0, stream>>>(x, Wq, q_raw, M, 2 * Cc, Cc);
    gemm64<<<dim3(2 * Cc / 64, M / 64), 256, 0, stream>>>(x, Wk, k_raw, M, 2 * Cc, Cc);
    gemm64<<<dim3(Cc / 64, M / 64), 256, 0, stream>>>(x, Wv, v_raw, M, Cc, Cc);

    qk_transform<<<(Bc * Hc * Tc * Dc) / 256, 256, 0, stream>>>(q_raw, q2, 0.125f);
    qk_transform<<<(Bc * Hc * Tc * Dc) / 256, 256, 0, stream>>>(k_raw, k2, 1.0f);
    vtrans<<<dim3(Tc / 64, Hc, Bc), 256, 0, stream>>>(v_raw, v2t);

    moire_attn_mfma<<<dim3(Tc / 64, Hc, Bc), 256, 0, stream>>>(q2, k2, v2t, theta, att);

    gemm64<<<dim3(Cc / 64, M / 64), 256, 0, stream>>>(att, Wo, out, M, Cc, Cc);
}

// Round 3
// 402.129 us; speedup vs baseline: 57.6499x; 2.4153x over previous
//
#include <hip/hip_runtime.h>
#include <hip/hip_bf16.h>
#include <math.h>

// Problem constants
#define Bc 2
#define Tc 2048
#define Cc 1024
#define Hc 16
#define Dc 64
// SCALE = 1/8, GAMMA = 8

typedef __attribute__((ext_vector_type(8))) short short8;   // 8 bf16 (4 VGPRs)
typedef __attribute__((ext_vector_type(4))) float f32x4;    // MFMA C/D frag

__device__ __forceinline__ short f2bf(float x) {
    unsigned u = __float_as_uint(x);
    u += 0x7fff + ((u >> 16) & 1);      // RNE
    return (short)(u >> 16);
}

// ---------------------------------------------------------------------------
// bf16 MFMA GEMM (m97 recipe): C[M,N] = A[M,K] @ Bt[N,K]^T
// 128x128 block tile, 4 waves (2x2), BK=32, global_load_lds width=16.
// Per wave per K-iter: 4 global_load_lds + 8 ds_read_b128 + 16 MFMA.
// ---------------------------------------------------------------------------
template <bool BF16_OUT>
__global__ __launch_bounds__(256) void gemm_bt_mfma(
    const short* __restrict__ A,    // M x K bf16 row-major
    const short* __restrict__ Bt,   // N x K bf16 row-major (= B^T)
    float* __restrict__ Cf,         // M x N f32   (if !BF16_OUT)
    short* __restrict__ Cb,         // M x N bf16  (if BF16_OUT)
    int M, int N, int K)
{
    __shared__ __attribute__((aligned(16))) short As[128 * 32];
    __shared__ __attribute__((aligned(16))) short Bs[128 * 32];

    const int tid = threadIdx.x;
    const int wave = tid >> 6, lane = tid & 63;
    const int quad = lane >> 4, c = lane & 15;
    const int wm = wave >> 1, wn = wave & 1;
    const int m0 = blockIdx.y * 128, n0 = blockIdx.x * 128;

    // staging: wave stages 32 rows of A and 32 rows of Bt (2 issues each,
    // 16 rows x 32 cols per issue = 1024 B; lane L -> row L>>2, col (L&3)*8)
    const int srow = lane >> 2;
    const int scol = (lane & 3) * 8;
    const short* Ag = A  + (size_t)(m0 + wave * 32 + srow) * K + scol;
    const short* Bg = Bt + (size_t)(n0 + wave * 32 + srow) * K + scol;
    short* AsW = As + (wave * 32) * 32;
    short* BsW = Bs + (wave * 32) * 32;

    f32x4 acc[4][4];
#pragma unroll
    for (int i = 0; i < 4; ++i)
#pragma unroll
        for (int j = 0; j < 4; ++j)
            acc[i][j] = (f32x4){0.f, 0.f, 0.f, 0.f};

    for (int k0 = 0; k0 < K; k0 += 32) {
        __syncthreads();                       // prev iter's reads done
#pragma unroll
        for (int i = 0; i < 2; ++i) {
            __builtin_amdgcn_global_load_lds(
                (const __attribute__((address_space(1))) void*)(Ag + k0 + (size_t)i * 16 * K),
                (__attribute__((address_space(3))) void*)(AsW + i * 16 * 32),
                16, 0, 0);
            __builtin_amdgcn_global_load_lds(
                (const __attribute__((address_space(1))) void*)(Bg + k0 + (size_t)i * 16 * K),
                (__attribute__((address_space(3))) void*)(BsW + i * 16 * 32),
                16, 0, 0);
        }
        __syncthreads();                       // drains vmcnt -> LDS valid

        short8 af[4], bf[4];
#pragma unroll
        for (int mt = 0; mt < 4; ++mt)
            af[mt] = *(const short8*)&As[(wm * 64 + mt * 16 + c) * 32 + quad * 8];
#pragma unroll
        for (int nt = 0; nt < 4; ++nt)
            bf[nt] = *(const short8*)&Bs[(wn * 64 + nt * 16 + c) * 32 + quad * 8];
#pragma unroll
        for (int mt = 0; mt < 4; ++mt)
#pragma unroll
            for (int nt = 0; nt < 4; ++nt)
                acc[mt][nt] = __builtin_amdgcn_mfma_f32_16x16x32_bf16(
                    af[mt], bf[nt], acc[mt][nt], 0, 0, 0);
    }

    // epilogue: D row = quad*4+reg (m), col = c (n)
#pragma unroll
    for (int mt = 0; mt < 4; ++mt) {
#pragma unroll
        for (int reg = 0; reg < 4; ++reg) {
            size_t row = m0 + wm * 64 + mt * 16 + quad * 4 + reg;
#pragma unroll
            for (int nt = 0; nt < 4; ++nt) {
                size_t col = n0 + wn * 64 + nt * 16 + c;
                if (BF16_OUT)
                    Cb[row * N + col] = f2bf(acc[mt][nt][reg]);
                else
                    Cf[row * N + col] = acc[mt][nt][reg];
            }
        }
    }
}

// ---------------------------------------------------------------------------
// x (B,T,C) f32 -> bf16, contiguous
// ---------------------------------------------------------------------------
__global__ __launch_bounds__(256) void xconv(const float* __restrict__ x,
                                             short* __restrict__ xb)
{
    int idx = blockIdx.x * 256 + threadIdx.x;
    float4 v = *(const float4*)&x[(size_t)idx * 4];
    short4 o = {f2bf(v.x), f2bf(v.y), f2bf(v.z), f2bf(v.w)};
    *(short4*)&xb[(size_t)idx * 4] = o;
}

// ---------------------------------------------------------------------------
// W (K,N) f32 -> Wt (N,K) bf16 (transpose + convert), 64x64 tiles
// ---------------------------------------------------------------------------
__global__ __launch_bounds__(256) void wtrans(const float* __restrict__ W,
                                              short* __restrict__ Wt,
                                              int K, int N)
{
    __shared__ short tile[64][80];
    const int n0 = blockIdx.x * 64, k0 = blockIdx.y * 64;
    const int tid = threadIdx.x;
#pragma unroll
    for (int i = 0; i < 4; ++i) {
        int e = i * 256 + tid;              // 0..1023
        int k = e >> 4, n4 = (e & 15) * 4;
        float4 v = *(const float4*)&W[(size_t)(k0 + k) * N + n0 + n4];
        tile[k][n4]     = f2bf(v.x);
        tile[k][n4 + 1] = f2bf(v.y);
        tile[k][n4 + 2] = f2bf(v.z);
        tile[k][n4 + 3] = f2bf(v.w);
    }
    __syncthreads();
#pragma unroll
    for (int i = 0; i < 16; ++i) {
        int e = i * 256 + tid;              // 0..4095
        int n = e >> 6, k = e & 63;
        Wt[(size_t)(n0 + n) * K + k0 + k] = tile[k][n];
    }
}

// ---------------------------------------------------------------------------
// raw (B,T,2C) f32 -> out2 (B,H,T,128) bf16 = [sp*cos(ph) | sp*sin(ph)] * scale
// ---------------------------------------------------------------------------
__global__ __launch_bounds__(256) void qk_transform(const float* __restrict__ raw,
                                                    short* __restrict__ out2,
                                                    float scale)
{
    int idx = blockIdx.x * 256 + threadIdx.x;   // B*H*T*64 = 2^22
    int d = idx & 63;
    int t = (idx >> 6) & (Tc - 1);
    int h = (idx >> 17) & (Hc - 1);
    int b = idx >> 21;
    size_t base = (size_t)(b * Tc + t) * (2 * Cc) + h * Dc + d;
    float amp = raw[base], ph = raw[base + Cc];
    float sp = fmaxf(amp, 0.f) + log1pf(expf(-fabsf(amp)));
    float sn, cs;
    sincosf(ph, &sn, &cs);
    size_t o = ((size_t)(b * Hc + h) * Tc + t) * 128 + d;
    out2[o]      = f2bf(sp * cs * scale);
    out2[o + 64] = f2bf(sp * sn * scale);
}

// ---------------------------------------------------------------------------
// v_bf (B,T,C) bf16 -> v2t (B,H,D,T) bf16 (head transpose)
// ---------------------------------------------------------------------------
__global__ __launch_bounds__(256) void vtrans_bf(const short* __restrict__ v_bf,
                                                 short* __restrict__ v2t)
{
    __shared__ __attribute__((aligned(16))) short tile[64][80];
    const int t0 = blockIdx.x * 64, h = blockIdx.y, b = blockIdx.z;
    const int tid = threadIdx.x;
#pragma unroll
    for (int i = 0; i < 2; ++i) {
        int e = i * 256 + tid;              // 0..511
        int t = e >> 3, d8 = (e & 7) * 8;
        *(short8*)&tile[t][d8] =
            *(const short8*)&v_bf[(size_t)(b * Tc + t0 + t) * Cc + h * Dc + d8];
    }
    __syncthreads();
#pragma unroll
    for (int i = 0; i < 16; ++i) {
        int e = i * 256 + tid;              // 0..4095
        int d = e >> 6, t = e & 63;
        v2t[((size_t)(b * Hc + h) * Dc + d) * Tc + t0 + t] = tile[t][d];
    }
}

// ---------------------------------------------------------------------------
// MFMA flash attention with post-MFMA theta gate (unchanged from R2 except
// bf16 output for the Wo GEMM).
// ---------------------------------------------------------------------------
__global__ __launch_bounds__(256, 4) void moire_attn_mfma(
    const short* __restrict__ q2, const short* __restrict__ k2,
    const short* __restrict__ v2t, const float* __restrict__ theta,
    short* __restrict__ att)
{
    __shared__ __attribute__((aligned(16))) short Ks[64 * 136];
    __shared__ __attribute__((aligned(16))) short Vt[64 * 72];
    __shared__ __attribute__((aligned(16))) short Ps[4 * 16 * 72];

    const int tid = threadIdx.x;
    const int wave = tid >> 6, lane = tid & 63;
    const int quad = lane >> 4, c = lane & 15;
    const int qx = blockIdx.x, h = blockIdx.y, b = blockIdx.z;
    const int q0 = qx * 64;
    const float th = theta[h];

    const int qrow = q0 + wave * 16 + c;
    const short* qp = q2 + ((size_t)(b * Hc + h) * Tc + qrow) * 128;
    short8 qf[4];
#pragma unroll
    for (int i = 0; i < 4; ++i)
        qf[i] = *(const short8*)(qp + i * 32 + quad * 8);

    f32x4 o_acc[4];
    float m_r[4], l_r[4];
#pragma unroll
    for (int i = 0; i < 4; ++i) {
        o_acc[i] = (f32x4){0.f, 0.f, 0.f, 0.f};
        m_r[i] = -INFINITY;
        l_r[i] = 0.f;
    }

    const short* k2b = k2 + (size_t)(b * Hc + h) * Tc * 128;
    const short* v2b = v2t + (size_t)(b * Hc + h) * Dc * Tc;
    short* Pw = &Ps[wave * 16 * 72];

    for (int jt = 0; jt <= qx; ++jt) {
        const int s0 = jt * 64;
#pragma unroll
        for (int i = 0; i < 4; ++i) {
            int ch = i * 256 + tid;
            int row = ch >> 4, c8 = (ch & 15) * 8;
            *(short8*)&Ks[row * 136 + c8] =
                *(const short8*)(k2b + (size_t)(s0 + row) * 128 + c8);
        }
#pragma unroll
        for (int i = 0; i < 2; ++i) {
            int ch = i * 256 + tid;
            int row = ch >> 3, c8 = (ch & 7) * 8;
            *(short8*)&Vt[row * 72 + c8] =
                *(const short8*)(v2b + (size_t)row * Tc + s0 + c8);
        }
        __syncthreads();

        f32x4 s_acc[4];
#pragma unroll
        for (int nt = 0; nt < 4; ++nt) {
            f32x4 acc = {0.f, 0.f, 0.f, 0.f};
#pragma unroll
            for (int kk = 0; kk < 4; ++kk) {
                short8 kf = *(const short8*)&Ks[(nt * 16 + c) * 136 + kk * 32 + quad * 8];
                acc = __builtin_amdgcn_mfma_f32_16x16x32_bf16(qf[kk], kf, acc, 0, 0, 0);
            }
            s_acc[nt] = acc;
        }

        const int t_base = q0 + wave * 16 + quad * 4;
        const bool diag = (jt == qx);
        float sv[4][4];
#pragma unroll
        for (int nt = 0; nt < 4; ++nt) {
            int s_g = s0 + nt * 16 + c;
#pragma unroll
            for (int reg = 0; reg < 4; ++reg) {
                int t_g = t_base + reg;
                float v = s_acc[nt][reg] * __cosf(th * 0.125f * (float)(s_g - t_g));
                if (diag && s_g > t_g) v = -INFINITY;
                sv[nt][reg] = v;
            }
        }

        float mn[4], al[4], rs[4];
#pragma unroll
        for (int reg = 0; reg < 4; ++reg) {
            float rm = fmaxf(fmaxf(sv[0][reg], sv[1][reg]),
                             fmaxf(sv[2][reg], sv[3][reg]));
#pragma unroll
            for (int off = 1; off < 16; off <<= 1)
                rm = fmaxf(rm, __shfl_xor(rm, off));
            mn[reg] = fmaxf(m_r[reg], rm);
            al[reg] = __expf(m_r[reg] - mn[reg]);
            rs[reg] = 0.f;
        }
#pragma unroll
        for (int nt = 0; nt < 4; ++nt)
#pragma unroll
            for (int reg = 0; reg < 4; ++reg) {
                float p = __expf(sv[nt][reg] - mn[reg]);
                rs[reg] += p;
                Pw[(quad * 4 + reg) * 72 + nt * 16 + c] = f2bf(p);
            }
#pragma unroll
        for (int reg = 0; reg < 4; ++reg) {
#pragma unroll
            for (int off = 1; off < 16; off <<= 1)
                rs[reg] += __shfl_xor(rs[reg], off);
            l_r[reg] = l_r[reg] * al[reg] + rs[reg];
            m_r[reg] = mn[reg];
        }
#pragma unroll
        for (int nt = 0; nt < 4; ++nt)
#pragma unroll
            for (int reg = 0; reg < 4; ++reg)
                o_acc[nt][reg] *= al[reg];

#pragma unroll
        for (int nt = 0; nt < 4; ++nt) {
            f32x4 acc = o_acc[nt];
#pragma unroll
            for (int kk = 0; kk < 2; ++kk) {
                short8 pf = *(const short8*)&Pw[c * 72 + kk * 32 + quad * 8];
                short8 vf = *(const short8*)&Vt[(nt * 16 + c) * 72 + kk * 32 + quad * 8];
                acc = __builtin_amdgcn_mfma_f32_16x16x32_bf16(pf, vf, acc, 0, 0, 0);
            }
            o_acc[nt] = acc;
        }
        __syncthreads();
    }

#pragma unroll
    for (int reg = 0; reg < 4; ++reg) {
        float inv = 1.f / l_r[reg];
        int t_g = q0 + wave * 16 + quad * 4 + reg;
#pragma unroll
        for (int nt = 0; nt < 4; ++nt)
            att[(size_t)(b * Tc + t_g) * Cc + h * Dc + nt * 16 + c] =
                f2bf(o_acc[nt][reg] * inv);
    }
}

// ---------------------------------------------------------------------------
extern "C" void kernel_launch(void* const* d_in, const int* in_sizes, int n_in,
                              void* d_out, int out_size, void* d_ws, size_t ws_size,
                              hipStream_t stream)
{
    const float* x     = (const float*)d_in[0];
    const float* Wq    = (const float*)d_in[1];
    const float* Wk    = (const float*)d_in[2];
    const float* Wv    = (const float*)d_in[3];
    const float* Wo    = (const float*)d_in[4];
    const float* theta = (const float*)d_in[5];
    float* out = (float*)d_out;

    const int M = Bc * Tc;                 // 4096
    char* ws = (char*)d_ws;
    const size_t MB = 1 << 20;
    // Workspace map (peak 108 MB; q2 aliases xb/Wqt/Wkt, k2 lives in d_out):
    short* xb    = (short*)(ws);            // [0,8)   x bf16 (4096x1024)
    short* Wqt   = (short*)(ws + 8 * MB);   // [8,12)  Wq^T bf16 (2048x1024)
    short* Wkt   = (short*)(ws + 12 * MB);  // [12,16) Wk^T bf16 (2048x1024)
    short* Wvt   = (short*)(ws + 16 * MB);  // [16,18) Wv^T bf16 (1024x1024)
    short* Wot   = (short*)(ws + 18 * MB);  // [18,20) Wo^T bf16 (1024x1024)
    float* q_raw = (float*)(ws + 20 * MB);  // [20,52) f32 (4096x2048)
    float* k_raw = (float*)(ws + 52 * MB);  // [52,84) f32 (4096x2048)
    short* v_bf  = (short*)(ws + 84 * MB);  // [84,92) bf16 (B,T,C)
    short* v2t   = (short*)(ws + 92 * MB);  // [92,100) bf16 (B,H,D,T)
    short* attb  = (short*)(ws + 100 * MB); // [100,108) bf16 (B,T,C)
    short* q2    = (short*)(ws);            // [0,16)  bf16 (B,H,T,128) -- after gemms
    short* k2    = (short*)d_out;           // 16 MB   bf16 (B,H,T,128) -- until final gemm

    // convert inputs to bf16
    xconv<<<(size_t)M * Cc / 1024, 256, 0, stream>>>(x, xb);
    wtrans<<<dim3(2 * Cc / 64, Cc / 64), 256, 0, stream>>>(Wq, Wqt, Cc, 2 * Cc);
    wtrans<<<dim3(2 * Cc / 64, Cc / 64), 256, 0, stream>>>(Wk, Wkt, Cc, 2 * Cc);
    wtrans<<<dim3(Cc / 64, Cc / 64), 256, 0, stream>>>(Wv, Wvt, Cc, Cc);
    wtrans<<<dim3(Cc / 64, Cc / 64), 256, 0, stream>>>(Wo, Wot, Cc, Cc);

    // projections (MFMA)
    gemm_bt_mfma<false><<<dim3(2 * Cc / 128, M / 128), 256, 0, stream>>>(
        xb, Wqt, q_raw, nullptr, M, 2 * Cc, Cc);
    gemm_bt_mfma<false><<<dim3(2 * Cc / 128, M / 128), 256, 0, stream>>>(
        xb, Wkt, k_raw, nullptr, M, 2 * Cc, Cc);
    gemm_bt_mfma<true><<<dim3(Cc / 128, M / 128), 256, 0, stream>>>(
        xb, Wvt, nullptr, v_bf, M, Cc, Cc);

    // transforms (q2 overwrites xb/Wqt/Wkt -- all dead now)
    qk_transform<<<(Bc * Hc * Tc * Dc) / 256, 256, 0, stream>>>(q_raw, q2, 0.125f);
    qk_transform<<<(Bc * Hc * Tc * Dc) / 256, 256, 0, stream>>>(k_raw, k2, 1.0f);
    vtrans_bf<<<dim3(Tc / 64, Hc, Bc), 256, 0, stream>>>(v_bf, v2t);

    // attention
    moire_attn_mfma<<<dim3(Tc / 64, Hc, Bc), 256, 0, stream>>>(q2, k2, v2t, theta, attb);

    // output projection (overwrites d_out/k2)
    gemm_bt_mfma<false><<<dim3(Cc / 128, M / 128), 256, 0, stream>>>(
        attb, Wot, out, nullptr, M, Cc, Cc);
}

// Round 4
// 313.766 us; speedup vs baseline: 73.8853x; 1.2816x over previous
//
#include <hip/hip_runtime.h>
#include <hip/hip_bf16.h>
#include <math.h>

// Problem constants
#define Bc 2
#define Tc 2048
#define Cc 1024
#define Hc 16
#define Dc 64
// SCALE = 1/8, GAMMA = 8

typedef __attribute__((ext_vector_type(8))) short short8;   // 8 bf16 (4 VGPRs)
typedef __attribute__((ext_vector_type(4))) float f32x4;    // MFMA C/D frag

__device__ __forceinline__ short f2bf(float x) {
    unsigned u = __float_as_uint(x);
    u += 0x7fff + ((u >> 16) & 1);      // RNE
    return (short)(u >> 16);
}
__device__ __forceinline__ unsigned pack2bf(float a, float b) {
    unsigned ua = __float_as_uint(a); ua += 0x7fff + ((ua >> 16) & 1);
    unsigned ub = __float_as_uint(b); ub += 0x7fff + ((ub >> 16) & 1);
    return (ua >> 16) | (ub & 0xffff0000u);
}

// ---------------------------------------------------------------------------
// bf16 MFMA GEMM (m97 recipe): C[M,N] = A[M,K] @ Bt[N,K]^T  (unchanged R3)
// ---------------------------------------------------------------------------
template <bool BF16_OUT>
__global__ __launch_bounds__(256) void gemm_bt_mfma(
    const short* __restrict__ A, const short* __restrict__ Bt,
    float* __restrict__ Cf, short* __restrict__ Cb, int M, int N, int K)
{
    __shared__ __attribute__((aligned(16))) short As[128 * 32];
    __shared__ __attribute__((aligned(16))) short Bs[128 * 32];

    const int tid = threadIdx.x;
    const int wave = tid >> 6, lane = tid & 63;
    const int quad = lane >> 4, c = lane & 15;
    const int wm = wave >> 1, wn = wave & 1;
    const int m0 = blockIdx.y * 128, n0 = blockIdx.x * 128;

    const int srow = lane >> 2;
    const int scol = (lane & 3) * 8;
    const short* Ag = A  + (size_t)(m0 + wave * 32 + srow) * K + scol;
    const short* Bg = Bt + (size_t)(n0 + wave * 32 + srow) * K + scol;
    short* AsW = As + (wave * 32) * 32;
    short* BsW = Bs + (wave * 32) * 32;

    f32x4 acc[4][4];
#pragma unroll
    for (int i = 0; i < 4; ++i)
#pragma unroll
        for (int j = 0; j < 4; ++j)
            acc[i][j] = (f32x4){0.f, 0.f, 0.f, 0.f};

    for (int k0 = 0; k0 < K; k0 += 32) {
        __syncthreads();
#pragma unroll
        for (int i = 0; i < 2; ++i) {
            __builtin_amdgcn_global_load_lds(
                (const __attribute__((address_space(1))) void*)(Ag + k0 + (size_t)i * 16 * K),
                (__attribute__((address_space(3))) void*)(AsW + i * 16 * 32), 16, 0, 0);
            __builtin_amdgcn_global_load_lds(
                (const __attribute__((address_space(1))) void*)(Bg + k0 + (size_t)i * 16 * K),
                (__attribute__((address_space(3))) void*)(BsW + i * 16 * 32), 16, 0, 0);
        }
        __syncthreads();

        short8 af[4], bf[4];
#pragma unroll
        for (int mt = 0; mt < 4; ++mt)
            af[mt] = *(const short8*)&As[(wm * 64 + mt * 16 + c) * 32 + quad * 8];
#pragma unroll
        for (int nt = 0; nt < 4; ++nt)
            bf[nt] = *(const short8*)&Bs[(wn * 64 + nt * 16 + c) * 32 + quad * 8];
#pragma unroll
        for (int mt = 0; mt < 4; ++mt)
#pragma unroll
            for (int nt = 0; nt < 4; ++nt)
                acc[mt][nt] = __builtin_amdgcn_mfma_f32_16x16x32_bf16(
                    af[mt], bf[nt], acc[mt][nt], 0, 0, 0);
    }

#pragma unroll
    for (int mt = 0; mt < 4; ++mt) {
#pragma unroll
        for (int reg = 0; reg < 4; ++reg) {
            size_t row = m0 + wm * 64 + mt * 16 + quad * 4 + reg;
#pragma unroll
            for (int nt = 0; nt < 4; ++nt) {
                size_t col = n0 + wn * 64 + nt * 16 + c;
                if (BF16_OUT) Cb[row * N + col] = f2bf(acc[mt][nt][reg]);
                else          Cf[row * N + col] = acc[mt][nt][reg];
            }
        }
    }
}

// ---------------------------------------------------------------------------
__global__ __launch_bounds__(256) void xconv(const float* __restrict__ x,
                                             short* __restrict__ xb)
{
    int idx = blockIdx.x * 256 + threadIdx.x;
    float4 v = *(const float4*)&x[(size_t)idx * 4];
    short4 o = {f2bf(v.x), f2bf(v.y), f2bf(v.z), f2bf(v.w)};
    *(short4*)&xb[(size_t)idx * 4] = o;
}

// ---------------------------------------------------------------------------
__global__ __launch_bounds__(256) void wtrans(const float* __restrict__ W,
                                              short* __restrict__ Wt, int K, int N)
{
    __shared__ short tile[64][80];
    const int n0 = blockIdx.x * 64, k0 = blockIdx.y * 64;
    const int tid = threadIdx.x;
#pragma unroll
    for (int i = 0; i < 4; ++i) {
        int e = i * 256 + tid;
        int k = e >> 4, n4 = (e & 15) * 4;
        float4 v = *(const float4*)&W[(size_t)(k0 + k) * N + n0 + n4];
        tile[k][n4]     = f2bf(v.x);
        tile[k][n4 + 1] = f2bf(v.y);
        tile[k][n4 + 2] = f2bf(v.z);
        tile[k][n4 + 3] = f2bf(v.w);
    }
    __syncthreads();
#pragma unroll
    for (int i = 0; i < 16; ++i) {
        int e = i * 256 + tid;
        int n = e >> 6, k = e & 63;
        Wt[(size_t)(n0 + n) * K + k0 + k] = tile[k][n];
    }
}

// ---------------------------------------------------------------------------
// qk_raw (B,T,4096) f32 [q cols 0..2047 | k cols 2048..4095]
//   -> out2 (B,H,T,128) bf16 = [sp*cos(ph) | sp*sin(ph)] * scale
// ---------------------------------------------------------------------------
__global__ __launch_bounds__(256) void qk_transform(const float* __restrict__ raw,
                                                    short* __restrict__ out2,
                                                    float scale, int colOff)
{
    int idx = blockIdx.x * 256 + threadIdx.x;   // B*H*T*64 = 2^22
    int d = idx & 63;
    int t = (idx >> 6) & (Tc - 1);
    int h = (idx >> 17) & (Hc - 1);
    int b = idx >> 21;
    size_t base = (size_t)(b * Tc + t) * 4096 + colOff + h * Dc + d;
    float amp = raw[base], ph = raw[base + Cc];
    float sp = fmaxf(amp, 0.f) + log1pf(expf(-fabsf(amp)));
    float sn, cs;
    sincosf(ph, &sn, &cs);
    size_t o = ((size_t)(b * Hc + h) * Tc + t) * 128 + d;
    out2[o]      = f2bf(sp * cs * scale);
    out2[o + 64] = f2bf(sp * sn * scale);
}

// ---------------------------------------------------------------------------
__global__ __launch_bounds__(256) void vtrans_bf(const short* __restrict__ v_bf,
                                                 short* __restrict__ v2t)
{
    __shared__ __attribute__((aligned(16))) short tile[64][80];
    const int t0 = blockIdx.x * 64, h = blockIdx.y, b = blockIdx.z;
    const int tid = threadIdx.x;
#pragma unroll
    for (int i = 0; i < 2; ++i) {
        int e = i * 256 + tid;
        int t = e >> 3, d8 = (e & 7) * 8;
        *(short8*)&tile[t][d8] =
            *(const short8*)&v_bf[(size_t)(b * Tc + t0 + t) * Cc + h * Dc + d8];
    }
    __syncthreads();
#pragma unroll
    for (int i = 0; i < 16; ++i) {
        int e = i * 256 + tid;
        int d = e >> 6, t = e & 63;
        v2t[((size_t)(b * Hc + h) * Dc + d) * Tc + t0 + t] = tile[t][d];
    }
}

// ---------------------------------------------------------------------------
// MFMA flash attention, v2: paired q-tiles (uniform work), double-buffered
// K/V staging via global_load_lds + XOR swizzle, S^T formulation, 1 barrier
// per K-tile. Grid (16, H, B), 256 threads = 4 waves x 16 q-rows per tile.
// ---------------------------------------------------------------------------
__global__ __launch_bounds__(256, 2) void moire_attn2(
    const short* __restrict__ q2, const short* __restrict__ k2,
    const short* __restrict__ v2t, const float* __restrict__ theta,
    short* __restrict__ att)
{
    __shared__ __attribute__((aligned(16))) short Ks[2][64 * 128];  // 32 KB
    __shared__ __attribute__((aligned(16))) short Vt[2][64 * 64];   // 16 KB
    __shared__ __attribute__((aligned(16))) short Ps[4][16 * 64];   //  8 KB

    const int tid = threadIdx.x;
    const int wave = tid >> 6, lane = tid & 63;
    const int quad = lane >> 4, c = lane & 15;
    const int p = blockIdx.x, h = blockIdx.y, b = blockIdx.z;
    const int qx[2] = {p, 31 - p};
    const int q0[2] = {p * 64, (31 - p) * 64};
    const float th = theta[h];

    const short* k2b = k2 + (size_t)(b * Hc + h) * Tc * 128;
    const short* v2b = v2t + (size_t)(b * Hc + h) * Dc * Tc;

    // Q B-frags (n = t): row q0[tx] + wave*16 + c, 4 K-chunks of 32
    short8 qf[2][4];
#pragma unroll
    for (int tx = 0; tx < 2; ++tx) {
        const short* qp = q2 + ((size_t)(b * Hc + h) * Tc + q0[tx] + wave * 16 + c) * 128;
#pragma unroll
        for (int i = 0; i < 4; ++i)
            qf[tx][i] = *(const short8*)(qp + i * 32 + quad * 8);
    }

    // theta gate: gate = cos(th/8*(s-t)) = csS*csT + snS*snT.
    // Per-lane t (column) constants; per-lane s values advanced by rotation.
    const int t_l = wave * 16 + c;     // local t within q-tile (same both tiles)
    float csT[2], snT[2];
#pragma unroll
    for (int tx = 0; tx < 2; ++tx) {
        float at = th * 0.125f * (float)(q0[tx] + t_l);
        csT[tx] = __cosf(at);
        snT[tx] = __sinf(at);
    }
    float csS[4][4], snS[4][4];
#pragma unroll
    for (int mt = 0; mt < 4; ++mt)
#pragma unroll
        for (int reg = 0; reg < 4; ++reg) {
            float as = th * 0.125f * (float)(mt * 16 + quad * 4 + reg);
            csS[mt][reg] = __cosf(as);
            snS[mt][reg] = __sinf(as);
        }
    const float cD = __cosf(8.f * th), sD = __sinf(8.f * th);  // per-tile rotation

    f32x4 oacc[2][4];
    float m_s[2] = {-INFINITY, -INFINITY}, l_s[2] = {0.f, 0.f};
#pragma unroll
    for (int tx = 0; tx < 2; ++tx)
#pragma unroll
        for (int nt = 0; nt < 4; ++nt)
            oacc[tx][nt] = (f32x4){0.f, 0.f, 0.f, 0.f};

    auto stage = [&](int jts) {
        short* KsB = &Ks[jts & 1][0];
        short* VtB = &Vt[jts & 1][0];
        const int s0 = jts * 64;
#pragma unroll
        for (int i = 0; i < 4; ++i) {           // Ks: 1024 16B chunks
            int ch = i * 256 + tid;
            int row = ch >> 4, j = ch & 15;
            const short* src = k2b + (size_t)(s0 + row) * 128 + ((j ^ (row & 15)) << 3);
            __builtin_amdgcn_global_load_lds(
                (const __attribute__((address_space(1))) void*)src,
                (__attribute__((address_space(3))) void*)(KsB + (i * 256 + wave * 64) * 8),
                16, 0, 0);
        }
#pragma unroll
        for (int i = 0; i < 2; ++i) {           // Vt: 512 16B chunks
            int ch = i * 256 + tid;
            int row = ch >> 3, j = ch & 7;
            const short* src = v2b + (size_t)row * Tc + s0 + ((j ^ (row & 7)) << 3);
            __builtin_amdgcn_global_load_lds(
                (const __attribute__((address_space(1))) void*)src,
                (__attribute__((address_space(3))) void*)(VtB + (i * 256 + wave * 64) * 8),
                16, 0, 0);
        }
    };

    stage(0);
    const int jtEnd = qx[1];
    for (int jt = 0; jt <= jtEnd; ++jt) {
        __syncthreads();                 // drains stage(jt); fences buffer reuse
        if (jt < jtEnd) stage(jt + 1);   // overlaps with compute below

        const short* KsB = &Ks[jt & 1][0];
        const short* VtB = &Vt[jt & 1][0];

        // S^T = K Q^T : kf is A-operand (m=s), qf is B-operand (n=t)
        const bool aAct = (jt <= qx[0]);
        f32x4 sA[4], sB[4];
#pragma unroll
        for (int mt = 0; mt < 4; ++mt) {
            sA[mt] = (f32x4){0.f, 0.f, 0.f, 0.f};
            sB[mt] = (f32x4){0.f, 0.f, 0.f, 0.f};
#pragma unroll
            for (int kk = 0; kk < 4; ++kk) {
                short8 kf = *(const short8*)&KsB[(mt * 16 + c) * 128 +
                                                 (((kk * 4 + quad) ^ c) << 3)];
                if (aAct) sA[mt] = __builtin_amdgcn_mfma_f32_16x16x32_bf16(
                                        kf, qf[0][kk], sA[mt], 0, 0, 0);
                sB[mt] = __builtin_amdgcn_mfma_f32_16x16x32_bf16(
                                        kf, qf[1][kk], sB[mt], 0, 0, 0);
            }
        }

#pragma unroll
        for (int tx = 0; tx < 2; ++tx) {
            if (tx == 0 && !aAct) continue;
            f32x4* sX = (tx == 0) ? sA : sB;
            const bool diag = (jt == qx[tx]);

            float sv[4][4];
#pragma unroll
            for (int mt = 0; mt < 4; ++mt)
#pragma unroll
                for (int reg = 0; reg < 4; ++reg) {
                    float gate = csS[mt][reg] * csT[tx] + snS[mt][reg] * snT[tx];
                    float v = sX[mt][reg] * gate;
                    if (diag && (mt * 16 + quad * 4 + reg) > t_l) v = -INFINITY;
                    sv[mt][reg] = v;
                }

            // per-lane column softmax (t = c): 15 in-lane + 2 cross-quad shfl
            float tm = sv[0][0];
#pragma unroll
            for (int mt = 0; mt < 4; ++mt)
#pragma unroll
                for (int reg = 0; reg < 4; ++reg)
                    tm = fmaxf(tm, sv[mt][reg]);
            tm = fmaxf(tm, __shfl_xor(tm, 16));
            tm = fmaxf(tm, __shfl_xor(tm, 32));
            float mn = fmaxf(m_s[tx], tm);
            float alpha = __expf(m_s[tx] - mn);
            float ps = 0.f;
#pragma unroll
            for (int mt = 0; mt < 4; ++mt) {
                float p0 = __expf(sv[mt][0] - mn);
                float p1 = __expf(sv[mt][1] - mn);
                float p2 = __expf(sv[mt][2] - mn);
                float p3 = __expf(sv[mt][3] - mn);
                ps += (p0 + p1) + (p2 + p3);
                uint2 pk = {pack2bf(p0, p1), pack2bf(p2, p3)};
                int slot = ((mt * 2 + (quad >> 1)) ^ (c & 7));
                *(uint2*)&Ps[wave][c * 64 + slot * 8 + (quad & 1) * 4] = pk;
            }
            ps += __shfl_xor(ps, 16);
            ps += __shfl_xor(ps, 32);
            l_s[tx] = l_s[tx] * alpha + ps;
            m_s[tx] = mn;

            // rescale O (row t = quad*4+reg needs alpha from lane quad*4+reg)
            float alr[4];
#pragma unroll
            for (int reg = 0; reg < 4; ++reg)
                alr[reg] = __shfl(alpha, quad * 4 + reg);
#pragma unroll
            for (int nt = 0; nt < 4; ++nt)
#pragma unroll
                for (int reg = 0; reg < 4; ++reg)
                    oacc[tx][nt][reg] *= alr[reg];

            // O += P V : pf A-operand (m=t) from Ps row c; vf B-operand (n=d)
            short8 pf[2];
#pragma unroll
            for (int kk = 0; kk < 2; ++kk)
                pf[kk] = *(const short8*)&Ps[wave][c * 64 +
                             (((kk * 4 + quad) ^ (c & 7)) << 3)];
#pragma unroll
            for (int nt = 0; nt < 4; ++nt)
#pragma unroll
                for (int kk = 0; kk < 2; ++kk) {
                    short8 vf = *(const short8*)&VtB[(nt * 16 + c) * 64 +
                                 (((kk * 4 + quad) ^ (c & 7)) << 3)];
                    oacc[tx][nt] = __builtin_amdgcn_mfma_f32_16x16x32_bf16(
                        pf[kk], vf, oacc[tx][nt], 0, 0, 0);
                }
        }

        // advance s-angles by one tile (rotation by 8*th)
#pragma unroll
        for (int mt = 0; mt < 4; ++mt)
#pragma unroll
            for (int reg = 0; reg < 4; ++reg) {
                float cs = csS[mt][reg], sn = snS[mt][reg];
                csS[mt][reg] = cs * cD - sn * sD;
                snS[mt][reg] = sn * cD + cs * sD;
            }
    }

    // epilogue: O[t][d], row t = quad*4+reg, col d = nt*16+c
#pragma unroll
    for (int tx = 0; tx < 2; ++tx) {
        float il = 1.f / l_s[tx];
        float ilr[4];
#pragma unroll
        for (int reg = 0; reg < 4; ++reg)
            ilr[reg] = __shfl(il, quad * 4 + reg);
#pragma unroll
        for (int reg = 0; reg < 4; ++reg) {
            int t_g = q0[tx] + wave * 16 + quad * 4 + reg;
#pragma unroll
            for (int nt = 0; nt < 4; ++nt)
                att[(size_t)(b * Tc + t_g) * Cc + h * Dc + nt * 16 + c] =
                    f2bf(oacc[tx][nt][reg] * ilr[reg]);
        }
    }
}

// ---------------------------------------------------------------------------
extern "C" void kernel_launch(void* const* d_in, const int* in_sizes, int n_in,
                              void* d_out, int out_size, void* d_ws, size_t ws_size,
                              hipStream_t stream)
{
    const float* x     = (const float*)d_in[0];
    const float* Wq    = (const float*)d_in[1];
    const float* Wk    = (const float*)d_in[2];
    const float* Wv    = (const float*)d_in[3];
    const float* Wo    = (const float*)d_in[4];
    const float* theta = (const float*)d_in[5];
    float* out = (float*)d_out;

    const int M = Bc * Tc;                 // 4096
    char* ws = (char*)d_ws;
    const size_t MB = 1 << 20;
    short* xb     = (short*)(ws);            // [0,8)   x bf16
    short* Wqt    = (short*)(ws + 8 * MB);   // [8,12)  Wq^T bf16 (rows 0..2047)
    short* Wkt    = (short*)(ws + 12 * MB);  // [12,16) Wk^T bf16 (rows 2048..4095, contiguous!)
    short* Wvt    = (short*)(ws + 16 * MB);  // [16,18)
    short* Wot    = (short*)(ws + 18 * MB);  // [18,20)
    float* qk_raw = (float*)(ws + 20 * MB);  // [20,84) f32 (4096 x 4096) merged q|k
    short* v_bf   = (short*)(ws + 84 * MB);  // [84,92)
    short* v2t    = (short*)(ws + 92 * MB);  // [92,100)
    short* attb   = (short*)(ws + 100 * MB); // [100,108)
    short* q2     = (short*)(ws);            // [0,16)  bf16 (B,H,T,128) after gemms
    short* k2     = (short*)d_out;           // 16 MB   bf16 (B,H,T,128) until final gemm

    xconv<<<(size_t)M * Cc / 1024, 256, 0, stream>>>(x, xb);
    wtrans<<<dim3(2 * Cc / 64, Cc / 64), 256, 0, stream>>>(Wq, Wqt, Cc, 2 * Cc);
    wtrans<<<dim3(2 * Cc / 64, Cc / 64), 256, 0, stream>>>(Wk, Wkt, Cc, 2 * Cc);
    wtrans<<<dim3(Cc / 64, Cc / 64), 256, 0, stream>>>(Wv, Wvt, Cc, Cc);
    wtrans<<<dim3(Cc / 64, Cc / 64), 256, 0, stream>>>(Wo, Wot, Cc, Cc);

    // merged Q|K projection: Bt = [Wqt; Wkt] (4096 x 1024), N = 4096
    gemm_bt_mfma<false><<<dim3(4096 / 128, M / 128), 256, 0, stream>>>(
        xb, Wqt, qk_raw, nullptr, M, 4096, Cc);
    gemm_bt_mfma<true><<<dim3(Cc / 128, M / 128), 256, 0, stream>>>(
        xb, Wvt, nullptr, v_bf, M, Cc, Cc);

    qk_transform<<<(Bc * Hc * Tc * Dc) / 256, 256, 0, stream>>>(qk_raw, q2, 0.125f, 0);
    qk_transform<<<(Bc * Hc * Tc * Dc) / 256, 256, 0, stream>>>(qk_raw, k2, 1.0f, 2048);
    vtrans_bf<<<dim3(Tc / 64, Hc, Bc), 256, 0, stream>>>(v_bf, v2t);

    moire_attn2<<<dim3(16, Hc, Bc), 256, 0, stream>>>(q2, k2, v2t, theta, attb);

    gemm_bt_mfma<false><<<dim3(Cc / 128, M / 128), 256, 0, stream>>>(
        attb, Wot, out, nullptr, M, Cc, Cc);
}